// Round 5
// baseline (32170.236 us; speedup 1.0000x reference)
//
#include <hip/hip_runtime.h>
#include <hip/hip_bf16.h>

// KHopfield on MI355X — ROUND 5 DIAGNOSTIC BUILD.
// All GEMMs are naive tiled f32 VALU kernels (no MFMA, no bf16 operands) to
// bisect a deterministic logic error: stats/orchestration kept identical to
// round 4. If this passes, the bug lives in the MFMA GEMM layer.

typedef __attribute__((ext_vector_type(4))) float f32x4;

constexpr int   Bq    = 2048;
constexpr int   Nm    = 8192;
constexpr int   Dd    = 512;
constexpr int   KK    = 5;
constexpr float BETA  = 1.0f;
constexpr int   STEPS = 2;
constexpr size_t PL   = (size_t)Bq * Dd;

#define DEV static __device__ __forceinline__

DEV float b2f(ushort u) { unsigned v = ((unsigned)u) << 16; float f; __builtin_memcpy(&f, &v, 4); return f; }
DEV ushort f2b(float f) { __hip_bfloat16 h = __float2bfloat16(f); ushort u; __builtin_memcpy(&u, &h, 2); return u; }
DEV float ldin(const void* p, int isf, size_t idx) {
    return isf ? ((const float*)p)[idx] : b2f(((const ushort*)p)[idx]);
}

// dtype probe: f32 low half-words decode as random-exponent bf16 (|v|>64/inf/NaN).
__global__ __launch_bounds__(256) void detect_k(const ushort* __restrict__ xin,
                                                int* __restrict__ flag) {
    __shared__ int sb;
    if (threadIdx.x == 0) sb = 0;
    __syncthreads();
    int bad = 0;
    for (int i = threadIdx.x; i < 1024; i += 256) {
        float v = b2f(xin[i]);
        if (!(fabsf(v) < 64.0f)) bad = 1;
    }
    if (bad) atomicOr(&sb, 1);
    __syncthreads();
    if (threadIdx.x == 0) flag[0] = sb;     // 1 => inputs are f32
}

// row norms straight from raw inputs
__global__ __launch_bounds__(256) void norms_k(const void* __restrict__ xin,
                                               const void* __restrict__ memin,
                                               const int* __restrict__ flag,
                                               float* __restrict__ x2,
                                               float* __restrict__ m2) {
    int row = blockIdx.x;
    int isf = flag[0];
    const void* src; size_t base; float* dst;
    if (row < Nm) { src = memin; base = (size_t)row * Dd; dst = m2 + row; }
    else          { src = xin; base = (size_t)(row - Nm) * Dd; dst = x2 + (row - Nm); }
    int tid = threadIdx.x, lane = tid & 63, wave = tid >> 6;
    float s = 0.f;
    for (int i = tid; i < Dd; i += 256) { float v = ldin(src, isf, base + i); s += v * v; }
    for (int off = 32; off; off >>= 1) s += __shfl_down(s, off, 64);
    __shared__ float ws[4];
    if (lane == 0) ws[wave] = s;
    __syncthreads();
    if (tid == 0) dst[0] = ws[0] + ws[1] + ws[2] + ws[3];
}

// f32 transpose of memories: MT[d][n] = mem[n][d]
__global__ __launch_bounds__(256) void transF_k(const void* __restrict__ memin,
                                                const int* __restrict__ flag,
                                                float* __restrict__ MT) {
    __shared__ float t[32][33];
    int n0 = blockIdx.x * 32, d0 = blockIdx.y * 32;
    int isf = flag[0];
    for (int c = threadIdx.x; c < 1024; c += 256) {
        int r = c >> 5, cc = c & 31;
        t[r][cc] = ldin(memin, isf, (size_t)(n0 + r) * Dd + d0 + cc);
    }
    __syncthreads();
    for (int c = threadIdx.x; c < 1024; c += 256) {
        int r = c >> 5, cc = c & 31;
        MT[(size_t)(d0 + r) * Nm + n0 + cc] = t[cc][r];
    }
}

// naive tiled dist: S[m][n] = -beta * max(a2[m] + m2[n] - 2*A[ab0+m]·mem[n], 0)
// A rows read at global row (ab0 + bb0 + r); a2/S indexed chunk-locally.
__global__ __launch_bounds__(256) void distF_k(const void* __restrict__ A,
                                               const int* __restrict__ flag, int aForceF,
                                               const float* __restrict__ MT,
                                               float* __restrict__ S,
                                               const float* __restrict__ a2,
                                               const float* __restrict__ m2,
                                               int ab0, float negBeta) {
    __shared__ float xs[32][33];
    const int n = blockIdx.x * 256 + threadIdx.x;
    const int bb0 = blockIdx.y * 32;
    const int isf = aForceF ? 1 : flag[0];
    float acc[32];
#pragma unroll
    for (int r = 0; r < 32; ++r) acc[r] = 0.f;
    for (int d0 = 0; d0 < Dd; d0 += 32) {
        for (int c = threadIdx.x; c < 1024; c += 256) {
            int r = c >> 5, cc = c & 31;
            xs[r][cc] = ldin(A, isf, (size_t)(ab0 + bb0 + r) * Dd + d0 + cc);
        }
        __syncthreads();
        for (int dd = 0; dd < 32; ++dd) {
            float mv = MT[(size_t)(d0 + dd) * Nm + n];
#pragma unroll
            for (int r = 0; r < 32; ++r) acc[r] += xs[r][dd] * mv;
        }
        __syncthreads();
    }
#pragma unroll
    for (int r = 0; r < 32; ++r) {
        float d = a2[bb0 + r] + m2[n] - 2.0f * acc[r];
        S[(size_t)(bb0 + r) * Nm + n] = negBeta * fmaxf(d, 0.0f);
    }
}

// naive weight GEMM: C[b][d] += sum_n w(S[b][n]) * mem[n][d]
// TRF 1: w = expf(s-p0)*p1 (softmax);  TRF 2: w = sigmoid(s+p0) (LML)
template <int TRF>
__global__ __launch_bounds__(256) void wgemmF_k(const float* __restrict__ Sx,
                                                const void* __restrict__ memin,
                                                const int* __restrict__ flag,
                                                const float* __restrict__ rowpar,
                                                float* __restrict__ C, int nSpl) {
    __shared__ float wt[32][33];
    const int d = blockIdx.x * 256 + threadIdx.x;   // [0, 512)
    const int bb0 = blockIdx.y * 32;
    const int nLen = Nm / nSpl, n0 = blockIdx.z * nLen;
    const int isf = flag[0];
    float acc[32];
#pragma unroll
    for (int r = 0; r < 32; ++r) acc[r] = 0.f;
    for (int nc = n0; nc < n0 + nLen; nc += 32) {
        for (int c = threadIdx.x; c < 1024; c += 256) {
            int r = c >> 5, cc = c & 31;
            float s = Sx[(size_t)(bb0 + r) * Nm + nc + cc];
            float p0 = rowpar[(bb0 + r) * 2 + 0];
            float p1 = rowpar[(bb0 + r) * 2 + 1];
            float w;
            if constexpr (TRF == 1) w = expf(s - p0) * p1;
            else                    w = 1.0f / (1.0f + expf(-(s + p0)));
            wt[r][cc] = w;
        }
        __syncthreads();
        for (int nn = 0; nn < 32; ++nn) {
            float mv = ldin(memin, isf, (size_t)(nc + nn) * Dd + d);
#pragma unroll
            for (int r = 0; r < 32; ++r) acc[r] += wt[r][nn] * mv;
        }
        __syncthreads();
    }
#pragma unroll
    for (int r = 0; r < 32; ++r)
        atomicAdd(&C[(size_t)(bb0 + r) * Dd + d], acc[r]);
}

// per-row: top-6 + softmax stats + 4x nu bisection (unchanged from round 4)
__global__ __launch_bounds__(256) void rowstats_k(const float* __restrict__ S,
                                                  float* __restrict__ stats) {
    int b = blockIdx.x, tid = threadIdx.x, lane = tid & 63, wave = tid >> 6;
    __shared__ float ls[Nm];
    __shared__ float tops[256 * 6];
    __shared__ float stop[6];
    __shared__ float wred[16];
    __shared__ float bcast[5];
    const float* srow = S + (size_t)b * Nm;
    for (int i = tid; i < Nm; i += 256) ls[i] = srow[i];
    __syncthreads();

    float tt[6];
#pragma unroll
    for (int q = 0; q < 6; ++q) tt[q] = -3.4e38f;
    for (int i = tid; i < Nm; i += 256) {
        float v = ls[i];
        if (v > tt[5]) {
            tt[5] = v;
#pragma unroll
            for (int q = 5; q > 0; --q)
                if (tt[q] > tt[q - 1]) { float tm = tt[q]; tt[q] = tt[q - 1]; tt[q - 1] = tm; }
        }
    }
#pragma unroll
    for (int q = 0; q < 6; ++q) tops[tid * 6 + q] = tt[q];
    __syncthreads();
    if (tid == 0) {
        float mt[6];
#pragma unroll
        for (int q = 0; q < 6; ++q) mt[q] = -3.4e38f;
        for (int i = 0; i < 256 * 6; ++i) {
            float v = tops[i];
            if (v > mt[5]) {
                mt[5] = v;
#pragma unroll
                for (int q = 5; q > 0; --q)
                    if (mt[q] > mt[q - 1]) { float tm = mt[q]; mt[q] = mt[q - 1]; mt[q - 1] = tm; }
            }
        }
#pragma unroll
        for (int q = 0; q < 6; ++q) stop[q] = mt[q];
    }
    __syncthreads();

    float smax = stop[0];
    float p = 0.f;
    for (int i = tid; i < Nm; i += 256) p += expf(ls[i] - smax);
    for (int off = 32; off; off >>= 1) p += __shfl_down(p, off, 64);
    if (lane == 0) wred[wave] = p;
    __syncthreads();
    if (tid == 0) bcast[4] = wred[0] + wred[1] + wred[2] + wred[3];
    __syncthreads();
    float denom = bcast[4];

    float lo[4], hi[4];
#pragma unroll
    for (int q = 0; q < 4; ++q) { lo[q] = -stop[q + 1] - 7.0f; hi[q] = -stop[q + 2] + 7.0f; }
    for (int it = 0; it < 48; ++it) {
        float mid[4], pp[4] = {0.f, 0.f, 0.f, 0.f};
#pragma unroll
        for (int q = 0; q < 4; ++q) mid[q] = 0.5f * (lo[q] + hi[q]);
        for (int i = tid; i < Nm; i += 256) {
            float v = ls[i];
#pragma unroll
            for (int q = 0; q < 4; ++q) pp[q] += 1.0f / (1.0f + expf(-(v + mid[q])));
        }
#pragma unroll
        for (int q = 0; q < 4; ++q) {
            float s = pp[q];
            for (int off = 32; off; off >>= 1) s += __shfl_down(s, off, 64);
            if (lane == 0) wred[wave * 4 + q] = s;
        }
        __syncthreads();
        if (tid == 0)
#pragma unroll
            for (int q = 0; q < 4; ++q) bcast[q] = wred[q] + wred[4 + q] + wred[8 + q] + wred[12 + q];
        __syncthreads();
#pragma unroll
        for (int q = 0; q < 4; ++q) {
            float f = bcast[q] - (float)(q + 2);
            if (f < 0.f) lo[q] = mid[q]; else hi[q] = mid[q];
        }
        __syncthreads();
    }
    if (tid == 0) {
        stats[b * 6 + 0] = smax;
        stats[b * 6 + 1] = denom;
#pragma unroll
        for (int q = 0; q < 4; ++q) stats[b * 6 + 2 + q] = 0.5f * (lo[q] + hi[q]);
    }
}

__global__ __launch_bounds__(256) void rowpar_stage1_k(const float* __restrict__ stats,
                                                       float* __restrict__ rowpar, int jj) {
    int b = blockIdx.x * 256 + threadIdx.x;
    if (b >= Bq) return;
    if (jj == 0) {
        rowpar[b * 2 + 0] = stats[b * 6 + 0];
        rowpar[b * 2 + 1] = 1.0f / stats[b * 6 + 1];
    } else {
        rowpar[b * 2 + 0] = stats[b * 6 + 1 + jj];
        rowpar[b * 2 + 1] = 0.0f;
    }
}

__global__ __launch_bounds__(256) void rowmax_denom_k(const float* __restrict__ S,
                                                      float* __restrict__ rowpar) {
    int b = blockIdx.x, tid = threadIdx.x, lane = tid & 63, wave = tid >> 6;
    __shared__ float ls[Nm];
    __shared__ float wred[4];
    __shared__ float bc[1];
    const float* srow = S + (size_t)b * Nm;
    for (int i = tid; i < Nm; i += 256) ls[i] = srow[i];
    __syncthreads();
    float mx = -3.4e38f;
    for (int i = tid; i < Nm; i += 256) mx = fmaxf(mx, ls[i]);
    for (int off = 32; off; off >>= 1) mx = fmaxf(mx, __shfl_down(mx, off, 64));
    if (lane == 0) wred[wave] = mx;
    __syncthreads();
    if (tid == 0) bc[0] = fmaxf(fmaxf(wred[0], wred[1]), fmaxf(wred[2], wred[3]));
    __syncthreads();
    mx = bc[0];
    float p = 0.f;
    for (int i = tid; i < Nm; i += 256) p += expf(ls[i] - mx);
    for (int off = 32; off; off >>= 1) p += __shfl_down(p, off, 64);
    __syncthreads();
    if (lane == 0) wred[wave] = p;
    __syncthreads();
    if (tid == 0) {
        rowpar[b * 2 + 0] = mx;
        rowpar[b * 2 + 1] = 1.0f / (wred[0] + wred[1] + wred[2] + wred[3]);
    }
}

// row norms of an f32 R plane
__global__ __launch_bounds__(256) void rnorm_k(const float* __restrict__ R,
                                               float* __restrict__ r2) {
    int b = blockIdx.x, tid = threadIdx.x, lane = tid & 63, wave = tid >> 6;
    float s = 0.f;
    for (int i = tid; i < Dd; i += 256) { float v = R[(size_t)b * Dd + i]; s += v * v; }
    for (int off = 32; off; off >>= 1) s += __shfl_down(s, off, 64);
    __shared__ float ws[4];
    if (lane == 0) ws[wave] = s;
    __syncthreads();
    if (tid == 0) r2[b] = ws[0] + ws[1] + ws[2] + ws[3];
}

__global__ __launch_bounds__(256) void combine_k(float* __restrict__ R) {
    size_t idx = (size_t)blockIdx.x * 256 + threadIdx.x;
    float r0 = R[idx], r1 = R[PL + idx], r2v = R[2 * PL + idx], r3 = R[3 * PL + idx], r4 = R[4 * PL + idx];
    R[PL + idx]     = r1 - r0;
    R[2 * PL + idx] = r2v - r1;
    R[3 * PL + idx] = r3 - r2v;
    R[4 * PL + idx] = r4 - r3;
}

__global__ __launch_bounds__(256) void final_k(const float* __restrict__ R,
                                               void* __restrict__ out,
                                               const int* __restrict__ flag) {
    size_t idx = (size_t)blockIdx.x * 256 + threadIdx.x;
    bool isf = flag[0] != 0;
#pragma unroll
    for (int j = 0; j < KK; ++j) {
        float v = R[(size_t)j * PL + idx];
        if (isf) ((float*)out)[idx * KK + j] = v;
        else     ((ushort*)out)[idx * KK + j] = f2b(v);
    }
}

extern "C" void kernel_launch(void* const* d_in, const int* in_sizes, int n_in,
                              void* d_out, int out_size, void* d_ws, size_t ws_size,
                              hipStream_t stream) {
    const void* xin   = d_in[0];
    const void* memin = d_in[1];

    const size_t MiB = 1048576ull, KiB = 1024ull;
    char* ws = (char*)d_ws;
    float* MT    = (float*)(ws + 0);             // 16 MiB [Dd][Nm] f32
    float* R     = (float*)(ws + 16 * MiB);      // 20 MiB [5][Bq][Dd] f32
    float* m2    = (float*)(ws + 36 * MiB);                 // 32 KiB
    float* x2    = (float*)(ws + 36 * MiB + 32 * KiB);      //  8 KiB
    float* r2    = (float*)(ws + 36 * MiB + 40 * KiB);      //  8 KiB
    float* stats = (float*)(ws + 36 * MiB + 48 * KiB);      // 48 KiB
    float* rpar  = (float*)(ws + 36 * MiB + 96 * KiB);      // 16 KiB
    int*   flag  = (int*)  (ws + 36 * MiB + 112 * KiB);     //  4 B
    float* S     = (float*)(ws + 36 * MiB + 128 * KiB);     // Bc * 32 KiB

    int Bc = 128;
    const int cand[5] = {2048, 1024, 512, 256, 128};
    for (int i = 0; i < 5; ++i)
        if (36 * MiB + 128 * KiB + (size_t)cand[i] * Nm * 4 <= ws_size) { Bc = cand[i]; break; }
    const int nChunk = Bq / Bc;
    const int nSpl = 2;

    detect_k<<<1, 256, 0, stream>>>((const ushort*)xin, flag);
    norms_k<<<Nm + Bq, 256, 0, stream>>>(xin, memin, flag, x2, m2);
    transF_k<<<dim3(Nm / 32, Dd / 32), 256, 0, stream>>>(memin, flag, MT);

    // ---- stage 1: dists, stats, 5 weight-GEMMs (per batch chunk) ----
    for (int c = 0; c < nChunk; ++c) {
        int b0 = c * Bc;
        distF_k<<<dim3(Nm / 256, Bc / 32), 256, 0, stream>>>(
            xin, flag, /*aForceF=*/0, MT, S, x2 + b0, m2, b0, -BETA);
        rowstats_k<<<Bc, 256, 0, stream>>>(S, stats + (size_t)b0 * 6);
        for (int jj = 0; jj < KK; ++jj) {
            float* Rj = R + (size_t)jj * PL + (size_t)b0 * Dd;
            rowpar_stage1_k<<<Bq / 256, 256, 0, stream>>>(stats, rpar, jj);
            hipMemsetAsync(Rj, 0, (size_t)Bc * Dd * 4, stream);
            if (jj == 0)
                wgemmF_k<1><<<dim3(Dd / 256, Bc / 32, nSpl), 256, 0, stream>>>(
                    S, memin, flag, rpar + (size_t)b0 * 2, Rj, nSpl);
            else
                wgemmF_k<2><<<dim3(Dd / 256, Bc / 32, nSpl), 256, 0, stream>>>(
                    S, memin, flag, rpar + (size_t)b0 * 2, Rj, nSpl);
        }
    }
    combine_k<<<(int)(PL / 256), 256, 0, stream>>>(R);

    // ---- hopfield refinement ----
    for (int st = 0; st < STEPS; ++st) {
        for (int jj = 0; jj < KK; ++jj) {
            float* Rj = R + (size_t)jj * PL;
            rnorm_k<<<Bq, 256, 0, stream>>>(Rj, r2);
            for (int c = 0; c < nChunk; ++c) {
                int b0 = c * Bc;
                distF_k<<<dim3(Nm / 256, Bc / 32), 256, 0, stream>>>(
                    Rj, flag, /*aForceF=*/1, MT, S, r2 + b0, m2, b0, -BETA);
                rowmax_denom_k<<<Bc, 256, 0, stream>>>(S, rpar + (size_t)b0 * 2);
                hipMemsetAsync(Rj + (size_t)b0 * Dd, 0, (size_t)Bc * Dd * 4, stream);
                wgemmF_k<1><<<dim3(Dd / 256, Bc / 32, nSpl), 256, 0, stream>>>(
                    S, memin, flag, rpar + (size_t)b0 * 2, Rj + (size_t)b0 * Dd, nSpl);
            }
        }
    }
    final_k<<<(int)(PL / 256), 256, 0, stream>>>(R, d_out, flag);
}

// Round 7
// 29993.347 us; speedup vs baseline: 1.0726x; 1.0726x over previous
//
#include <hip/hip_runtime.h>
#include <hip/hip_bf16.h>

// KHopfield on MI355X — round 7: round-5-verified naive f32 GEMMs + fast
// candidate-set LML bisection (f32-lossless truncation: elements below
// stop[5]-40 have sigmoid < e^-33, rounding to 0 in the reference's own f32
// sum). MFMA dist path reverted pending re-derivation (round-6 post-mortem:
// hi/lo split path produced plain-bf16-grade dist errors).

constexpr int   Bq    = 2048;
constexpr int   Nm    = 8192;
constexpr int   Dd    = 512;
constexpr int   KK    = 5;
constexpr float BETA  = 1.0f;
constexpr int   STEPS = 2;
constexpr size_t PL   = (size_t)Bq * Dd;

#define DEV static __device__ __forceinline__

DEV float b2f(ushort u) { unsigned v = ((unsigned)u) << 16; float f; __builtin_memcpy(&f, &v, 4); return f; }
DEV ushort f2b(float f) { __hip_bfloat16 h = __float2bfloat16(f); ushort u; __builtin_memcpy(&u, &h, 2); return u; }
DEV float ldin(const void* p, int isf, size_t idx) {
    return isf ? ((const float*)p)[idx] : b2f(((const ushort*)p)[idx]);
}

__global__ __launch_bounds__(256) void detect_k(const ushort* __restrict__ xin,
                                                int* __restrict__ flag) {
    __shared__ int sb;
    if (threadIdx.x == 0) sb = 0;
    __syncthreads();
    int bad = 0;
    for (int i = threadIdx.x; i < 1024; i += 256) {
        float v = b2f(xin[i]);
        if (!(fabsf(v) < 64.0f)) bad = 1;
    }
    if (bad) atomicOr(&sb, 1);
    __syncthreads();
    if (threadIdx.x == 0) flag[0] = sb;     // 1 => inputs are f32
}

__global__ __launch_bounds__(256) void norms_k(const void* __restrict__ xin,
                                               const void* __restrict__ memin,
                                               const int* __restrict__ flag,
                                               float* __restrict__ x2,
                                               float* __restrict__ m2) {
    int row = blockIdx.x;
    int isf = flag[0];
    const void* src; size_t base; float* dst;
    if (row < Nm) { src = memin; base = (size_t)row * Dd; dst = m2 + row; }
    else          { src = xin; base = (size_t)(row - Nm) * Dd; dst = x2 + (row - Nm); }
    int tid = threadIdx.x, lane = tid & 63, wave = tid >> 6;
    float s = 0.f;
    for (int i = tid; i < Dd; i += 256) { float v = ldin(src, isf, base + i); s += v * v; }
    for (int off = 32; off; off >>= 1) s += __shfl_down(s, off, 64);
    __shared__ float ws[4];
    if (lane == 0) ws[wave] = s;
    __syncthreads();
    if (tid == 0) dst[0] = ws[0] + ws[1] + ws[2] + ws[3];
}

// f32 transpose of memories: MT[d][n] = mem[n][d]
__global__ __launch_bounds__(256) void transF_k(const void* __restrict__ memin,
                                                const int* __restrict__ flag,
                                                float* __restrict__ MT) {
    __shared__ float t[32][33];
    int n0 = blockIdx.x * 32, d0 = blockIdx.y * 32;
    int isf = flag[0];
    for (int c = threadIdx.x; c < 1024; c += 256) {
        int r = c >> 5, cc = c & 31;
        t[r][cc] = ldin(memin, isf, (size_t)(n0 + r) * Dd + d0 + cc);
    }
    __syncthreads();
    for (int c = threadIdx.x; c < 1024; c += 256) {
        int r = c >> 5, cc = c & 31;
        MT[(size_t)(d0 + r) * Nm + n0 + cc] = t[cc][r];
    }
}

// naive tiled dist: S[m][n] = -beta * max(a2[m] + m2[n] - 2*A[ab0+m]·mem[n], 0)
__global__ __launch_bounds__(256) void distF_k(const void* __restrict__ A,
                                               const int* __restrict__ flag, int aForceF,
                                               const float* __restrict__ MT,
                                               float* __restrict__ S,
                                               const float* __restrict__ a2,
                                               const float* __restrict__ m2,
                                               int ab0, float negBeta) {
    __shared__ float xs[32][33];
    const int n = blockIdx.x * 256 + threadIdx.x;
    const int bb0 = blockIdx.y * 32;
    const int isf = aForceF ? 1 : flag[0];
    float acc[32];
#pragma unroll
    for (int r = 0; r < 32; ++r) acc[r] = 0.f;
    for (int d0 = 0; d0 < Dd; d0 += 32) {
        for (int c = threadIdx.x; c < 1024; c += 256) {
            int r = c >> 5, cc = c & 31;
            xs[r][cc] = ldin(A, isf, (size_t)(ab0 + bb0 + r) * Dd + d0 + cc);
        }
        __syncthreads();
        for (int dd = 0; dd < 32; ++dd) {
            float mv = MT[(size_t)(d0 + dd) * Nm + n];
#pragma unroll
            for (int r = 0; r < 32; ++r) acc[r] += xs[r][dd] * mv;
        }
        __syncthreads();
    }
#pragma unroll
    for (int r = 0; r < 32; ++r) {
        float d = a2[bb0 + r] + m2[n] - 2.0f * acc[r];
        S[(size_t)(bb0 + r) * Nm + n] = negBeta * fmaxf(d, 0.0f);
    }
}

// naive weight GEMM: C[b][d] += sum_n w(S[b][n]) * mem[n][d]
// TRF 1: w = expf(s-p0)*p1 (softmax);  TRF 2: w = sigmoid(s+p0) (LML)
template <int TRF>
__global__ __launch_bounds__(256) void wgemmF_k(const float* __restrict__ Sx,
                                                const void* __restrict__ memin,
                                                const int* __restrict__ flag,
                                                const float* __restrict__ rowpar,
                                                float* __restrict__ C, int nSpl) {
    __shared__ float wt[32][33];
    const int d = blockIdx.x * 256 + threadIdx.x;
    const int bb0 = blockIdx.y * 32;
    const int nLen = Nm / nSpl, n0 = blockIdx.z * nLen;
    const int isf = flag[0];
    float acc[32];
#pragma unroll
    for (int r = 0; r < 32; ++r) acc[r] = 0.f;
    for (int nc = n0; nc < n0 + nLen; nc += 32) {
        for (int c = threadIdx.x; c < 1024; c += 256) {
            int r = c >> 5, cc = c & 31;
            float s = Sx[(size_t)(bb0 + r) * Nm + nc + cc];
            float p0 = rowpar[(bb0 + r) * 2 + 0];
            float p1 = rowpar[(bb0 + r) * 2 + 1];
            float w;
            if constexpr (TRF == 1) w = expf(s - p0) * p1;
            else                    w = 1.0f / (1.0f + expf(-(s + p0)));
            wt[r][cc] = w;
        }
        __syncthreads();
        for (int nn = 0; nn < 32; ++nn) {
            float mv = ldin(memin, isf, (size_t)(nc + nn) * Dd + d);
#pragma unroll
            for (int r = 0; r < 32; ++r) acc[r] += wt[r][nn] * mv;
        }
        __syncthreads();
    }
#pragma unroll
    for (int r = 0; r < 32; ++r)
        atomicAdd(&C[(size_t)(bb0 + r) * Dd + d], acc[r]);
}

// per-row: top-6 + denom + candidate-set bisection (f32-lossless truncation)
__global__ __launch_bounds__(256) void rowstats_k(const float* __restrict__ S,
                                                  float* __restrict__ stats) {
    int b = blockIdx.x, tid = threadIdx.x, lane = tid & 63, wave = tid >> 6;
    __shared__ float cbuf[1024];
    __shared__ int   ccnt;
    __shared__ float tops[256 * 6];
    __shared__ float stop[6];
    __shared__ float wred[16];
    __shared__ float bcast[5];
    const float* srow = S + (size_t)b * Nm;

    float tt[6];
#pragma unroll
    for (int q = 0; q < 6; ++q) tt[q] = -3.4e38f;
    for (int i = tid; i < Nm; i += 256) {
        float v = srow[i];
        if (v > tt[5]) {
            tt[5] = v;
#pragma unroll
            for (int q = 5; q > 0; --q)
                if (tt[q] > tt[q - 1]) { float tm = tt[q]; tt[q] = tt[q - 1]; tt[q - 1] = tm; }
        }
    }
#pragma unroll
    for (int q = 0; q < 6; ++q) tops[tid * 6 + q] = tt[q];
    if (tid == 0) ccnt = 0;
    __syncthreads();
    if (tid == 0) {
        float mt[6];
#pragma unroll
        for (int q = 0; q < 6; ++q) mt[q] = -3.4e38f;
        for (int i = 0; i < 256 * 6; ++i) {
            float v = tops[i];
            if (v > mt[5]) {
                mt[5] = v;
#pragma unroll
                for (int q = 5; q > 0; --q)
                    if (mt[q] > mt[q - 1]) { float tm = mt[q]; mt[q] = mt[q - 1]; mt[q - 1] = tm; }
            }
        }
#pragma unroll
        for (int q = 0; q < 6; ++q) stop[q] = mt[q];
    }
    __syncthreads();

    float smax = stop[0];
    float cutoff = stop[5] - 40.0f;
    float p = 0.f;
    for (int i = tid; i < Nm; i += 256) {
        float v = srow[i];
        p += expf(v - smax);
        if (v >= cutoff) {
            int idx = atomicAdd(&ccnt, 1);
            if (idx < 1024) cbuf[idx] = v;
        }
    }
    for (int off = 32; off; off >>= 1) p += __shfl_down(p, off, 64);
    if (lane == 0) wred[wave] = p;
    __syncthreads();
    if (tid == 0) bcast[4] = wred[0] + wred[1] + wred[2] + wred[3];
    __syncthreads();
    float denom = bcast[4];
    int cnt = min(ccnt, 1024);

    float lo[4], hi[4];
#pragma unroll
    for (int q = 0; q < 4; ++q) { lo[q] = -stop[q + 1] - 7.0f; hi[q] = -stop[q + 2] + 7.0f; }
    for (int it = 0; it < 48; ++it) {
        float mid[4], pp[4] = {0.f, 0.f, 0.f, 0.f};
#pragma unroll
        for (int q = 0; q < 4; ++q) mid[q] = 0.5f * (lo[q] + hi[q]);
        for (int i = tid; i < cnt; i += 256) {
            float v = cbuf[i];
#pragma unroll
            for (int q = 0; q < 4; ++q) pp[q] += 1.0f / (1.0f + expf(-(v + mid[q])));
        }
#pragma unroll
        for (int q = 0; q < 4; ++q) {
            float s = pp[q];
            for (int off = 32; off; off >>= 1) s += __shfl_down(s, off, 64);
            if (lane == 0) wred[wave * 4 + q] = s;
        }
        __syncthreads();
        if (tid == 0)
#pragma unroll
            for (int q = 0; q < 4; ++q) bcast[q] = wred[q] + wred[4 + q] + wred[8 + q] + wred[12 + q];
        __syncthreads();
#pragma unroll
        for (int q = 0; q < 4; ++q) {
            float f = bcast[q] - (float)(q + 2);
            if (f < 0.f) lo[q] = mid[q]; else hi[q] = mid[q];
        }
        __syncthreads();
    }
    if (tid == 0) {
        stats[b * 6 + 0] = smax;
        stats[b * 6 + 1] = denom;
#pragma unroll
        for (int q = 0; q < 4; ++q) stats[b * 6 + 2 + q] = 0.5f * (lo[q] + hi[q]);
    }
}

__global__ __launch_bounds__(256) void rowpar_stage1_k(const float* __restrict__ stats,
                                                       float* __restrict__ rowpar, int jj) {
    int b = blockIdx.x * 256 + threadIdx.x;
    if (b >= Bq) return;
    if (jj == 0) {
        rowpar[b * 2 + 0] = stats[b * 6 + 0];
        rowpar[b * 2 + 1] = 1.0f / stats[b * 6 + 1];
    } else {
        rowpar[b * 2 + 0] = stats[b * 6 + 1 + jj];
        rowpar[b * 2 + 1] = 0.0f;
    }
}

__global__ __launch_bounds__(256) void rowmax_denom_k(const float* __restrict__ S,
                                                      float* __restrict__ rowpar) {
    int b = blockIdx.x, tid = threadIdx.x, lane = tid & 63, wave = tid >> 6;
    __shared__ float wred[4];
    __shared__ float bc[1];
    const float* srow = S + (size_t)b * Nm;
    float mx = -3.4e38f;
    for (int i = tid; i < Nm; i += 256) mx = fmaxf(mx, srow[i]);
    for (int off = 32; off; off >>= 1) mx = fmaxf(mx, __shfl_down(mx, off, 64));
    if (lane == 0) wred[wave] = mx;
    __syncthreads();
    if (tid == 0) bc[0] = fmaxf(fmaxf(wred[0], wred[1]), fmaxf(wred[2], wred[3]));
    __syncthreads();
    mx = bc[0];
    float p = 0.f;
    for (int i = tid; i < Nm; i += 256) p += expf(srow[i] - mx);
    for (int off = 32; off; off >>= 1) p += __shfl_down(p, off, 64);
    __syncthreads();
    if (lane == 0) wred[wave] = p;
    __syncthreads();
    if (tid == 0) {
        rowpar[b * 2 + 0] = mx;
        rowpar[b * 2 + 1] = 1.0f / (wred[0] + wred[1] + wred[2] + wred[3]);
    }
}

__global__ __launch_bounds__(256) void rnorm_k(const float* __restrict__ R,
                                               float* __restrict__ r2) {
    int b = blockIdx.x, tid = threadIdx.x, lane = tid & 63, wave = tid >> 6;
    float s = 0.f;
    for (int i = tid; i < Dd; i += 256) { float v = R[(size_t)b * Dd + i]; s += v * v; }
    for (int off = 32; off; off >>= 1) s += __shfl_down(s, off, 64);
    __shared__ float ws[4];
    if (lane == 0) ws[wave] = s;
    __syncthreads();
    if (tid == 0) r2[b] = ws[0] + ws[1] + ws[2] + ws[3];
}

__global__ __launch_bounds__(256) void combine_k(float* __restrict__ R) {
    size_t idx = (size_t)blockIdx.x * 256 + threadIdx.x;
    float r0 = R[idx], r1 = R[PL + idx], r2v = R[2 * PL + idx], r3 = R[3 * PL + idx], r4 = R[4 * PL + idx];
    R[PL + idx]     = r1 - r0;
    R[2 * PL + idx] = r2v - r1;
    R[3 * PL + idx] = r3 - r2v;
    R[4 * PL + idx] = r4 - r3;
}

__global__ __launch_bounds__(256) void final_k(const float* __restrict__ R,
                                               void* __restrict__ out,
                                               const int* __restrict__ flag) {
    size_t idx = (size_t)blockIdx.x * 256 + threadIdx.x;
    bool isf = flag[0] != 0;
#pragma unroll
    for (int j = 0; j < KK; ++j) {
        float v = R[(size_t)j * PL + idx];
        if (isf) ((float*)out)[idx * KK + j] = v;
        else     ((ushort*)out)[idx * KK + j] = f2b(v);
    }
}

extern "C" void kernel_launch(void* const* d_in, const int* in_sizes, int n_in,
                              void* d_out, int out_size, void* d_ws, size_t ws_size,
                              hipStream_t stream) {
    const void* xin   = d_in[0];
    const void* memin = d_in[1];

    const size_t MiB = 1048576ull, KiB = 1024ull;
    char* ws = (char*)d_ws;
    float* MT    = (float*)(ws + 0);             // 16 MiB [Dd][Nm] f32
    float* R     = (float*)(ws + 16 * MiB);      // 20 MiB [5][Bq][Dd] f32
    float* m2    = (float*)(ws + 36 * MiB);                 // 32 KiB
    float* x2    = (float*)(ws + 36 * MiB + 32 * KiB);      //  8 KiB
    float* r2    = (float*)(ws + 36 * MiB + 40 * KiB);      //  8 KiB
    float* stats = (float*)(ws + 36 * MiB + 48 * KiB);      // 48 KiB
    float* rpar  = (float*)(ws + 36 * MiB + 96 * KiB);      // 16 KiB
    int*   flag  = (int*)  (ws + 36 * MiB + 112 * KiB);     //  4 B
    float* S     = (float*)(ws + 36 * MiB + 128 * KiB);     // Bc * 32 KiB

    int Bc = 128;
    const int cand[5] = {2048, 1024, 512, 256, 128};
    for (int i = 0; i < 5; ++i)
        if (36 * MiB + 128 * KiB + (size_t)cand[i] * Nm * 4 <= ws_size) { Bc = cand[i]; break; }
    const int nChunk = Bq / Bc;
    int nSpl = 4096 / Bc; if (nSpl < 2) nSpl = 2; if (nSpl > 16) nSpl = 16;

    detect_k<<<1, 256, 0, stream>>>((const ushort*)xin, flag);
    norms_k<<<Nm + Bq, 256, 0, stream>>>(xin, memin, flag, x2, m2);
    transF_k<<<dim3(Nm / 32, Dd / 32), 256, 0, stream>>>(memin, flag, MT);

    // ---- stage 1 ----
    for (int c = 0; c < nChunk; ++c) {
        int b0 = c * Bc;
        distF_k<<<dim3(Nm / 256, Bc / 32), 256, 0, stream>>>(
            xin, flag, /*aForceF=*/0, MT, S, x2 + b0, m2, b0, -BETA);
        rowstats_k<<<Bc, 256, 0, stream>>>(S, stats + (size_t)b0 * 6);
        for (int jj = 0; jj < KK; ++jj) {
            float* Rj = R + (size_t)jj * PL + (size_t)b0 * Dd;
            rowpar_stage1_k<<<Bq / 256, 256, 0, stream>>>(stats, rpar, jj);
            hipMemsetAsync(Rj, 0, (size_t)Bc * Dd * 4, stream);
            if (jj == 0)
                wgemmF_k<1><<<dim3(Dd / 256, Bc / 32, nSpl), 256, 0, stream>>>(
                    S, memin, flag, rpar + (size_t)b0 * 2, Rj, nSpl);
            else
                wgemmF_k<2><<<dim3(Dd / 256, Bc / 32, nSpl), 256, 0, stream>>>(
                    S, memin, flag, rpar + (size_t)b0 * 2, Rj, nSpl);
        }
    }
    combine_k<<<(int)(PL / 256), 256, 0, stream>>>(R);

    // ---- hopfield refinement ----
    for (int st = 0; st < STEPS; ++st) {
        for (int jj = 0; jj < KK; ++jj) {
            float* Rj = R + (size_t)jj * PL;
            rnorm_k<<<Bq, 256, 0, stream>>>(Rj, r2);
            for (int c = 0; c < nChunk; ++c) {
                int b0 = c * Bc;
                distF_k<<<dim3(Nm / 256, Bc / 32), 256, 0, stream>>>(
                    Rj, flag, /*aForceF=*/1, MT, S, r2 + b0, m2, b0, -BETA);
                rowmax_denom_k<<<Bc, 256, 0, stream>>>(S, rpar + (size_t)b0 * 2);
                hipMemsetAsync(Rj + (size_t)b0 * Dd, 0, (size_t)Bc * Dd * 4, stream);
                wgemmF_k<1><<<dim3(Dd / 256, Bc / 32, nSpl), 256, 0, stream>>>(
                    S, memin, flag, rpar + (size_t)b0 * 2, Rj + (size_t)b0 * Dd, nSpl);
            }
        }
    }
    final_k<<<(int)(PL / 256), 256, 0, stream>>>(R, d_out, flag);
}

// Round 8
// 10048.019 us; speedup vs baseline: 3.2016x; 2.9850x over previous
//
#include <hip/hip_runtime.h>
#include <hip/hip_bf16.h>

// KHopfield on MI355X — round 8: efficient f32 register-blocked GEMMs
// (64x64 tile, transposed LDS staging, float4 LDS reads), atomic-free
// split-K via partial planes in d_out's dead tail + deterministic reduce,
// candidate-set LML bisection (r7-validated). No memsets, no atomics.

constexpr int   Bq    = 2048;
constexpr int   Nm    = 8192;
constexpr int   Dd    = 512;
constexpr int   KK    = 5;
constexpr float BETA  = 1.0f;
constexpr int   STEPS = 2;
constexpr int   KS    = 8;                 // wgemm split-K planes
constexpr size_t PL   = (size_t)Bq * Dd;

#define DEV static __device__ __forceinline__

DEV float b2f(ushort u) { unsigned v = ((unsigned)u) << 16; float f; __builtin_memcpy(&f, &v, 4); return f; }
DEV ushort f2b(float f) { __hip_bfloat16 h = __float2bfloat16(f); ushort u; __builtin_memcpy(&u, &h, 2); return u; }
DEV float ldin(const void* p, int isf, size_t idx) {
    return isf ? ((const float*)p)[idx] : b2f(((const ushort*)p)[idx]);
}

__global__ __launch_bounds__(256) void detect_k(const ushort* __restrict__ xin,
                                                int* __restrict__ flag) {
    __shared__ int sb;
    if (threadIdx.x == 0) sb = 0;
    __syncthreads();
    int bad = 0;
    for (int i = threadIdx.x; i < 1024; i += 256) {
        float v = b2f(xin[i]);
        if (!(fabsf(v) < 64.0f)) bad = 1;
    }
    if (bad) atomicOr(&sb, 1);
    __syncthreads();
    if (threadIdx.x == 0) flag[0] = sb;     // 1 => inputs are f32
}

__global__ __launch_bounds__(256) void norms_k(const void* __restrict__ xin,
                                               const void* __restrict__ memin,
                                               const int* __restrict__ flag,
                                               float* __restrict__ x2,
                                               float* __restrict__ m2) {
    int row = blockIdx.x;
    int isf = flag[0];
    const void* src; size_t base; float* dst;
    if (row < Nm) { src = memin; base = (size_t)row * Dd; dst = m2 + row; }
    else          { src = xin; base = (size_t)(row - Nm) * Dd; dst = x2 + (row - Nm); }
    int tid = threadIdx.x, lane = tid & 63, wave = tid >> 6;
    float s = 0.f;
    for (int i = tid; i < Dd; i += 256) { float v = ldin(src, isf, base + i); s += v * v; }
    for (int off = 32; off; off >>= 1) s += __shfl_down(s, off, 64);
    __shared__ float ws[4];
    if (lane == 0) ws[wave] = s;
    __syncthreads();
    if (tid == 0) dst[0] = ws[0] + ws[1] + ws[2] + ws[3];
}

// ---------- dist GEMM: 64x64 tile, S[m][n] = -beta*max(a2[m]+m2[n]-2*A·mem, 0)
__global__ __launch_bounds__(256) void distF2_k(const void* __restrict__ A,
                                                const int* __restrict__ flag, int aForceF,
                                                const void* __restrict__ memin,
                                                float* __restrict__ S,
                                                const float* __restrict__ a2,
                                                const float* __restrict__ m2,
                                                int ab0, float negBeta) {
    __shared__ float As[16][68];   // [k][m]
    __shared__ float Bs[16][68];   // [k][n]
    const int tid = threadIdx.x, tx = tid & 15, ty = tid >> 4;
    const int m0 = blockIdx.y * 64, n0 = blockIdx.x * 64;
    const int isfA = aForceF ? 1 : flag[0];
    const int isfB = flag[0];

    float acc[4][4];
#pragma unroll
    for (int i = 0; i < 4; ++i)
#pragma unroll
        for (int j = 0; j < 4; ++j) acc[i][j] = 0.f;

    for (int d0 = 0; d0 < Dd; d0 += 16) {
#pragma unroll
        for (int c = tid; c < 1024; c += 256) {
            int r = c >> 4, k = c & 15;
            As[k][r] = ldin(A, isfA, (size_t)(ab0 + m0 + r) * Dd + d0 + k);
            Bs[k][r] = ldin(memin, isfB, (size_t)(n0 + r) * Dd + d0 + k);
        }
        __syncthreads();
#pragma unroll
        for (int k = 0; k < 16; ++k) {
            float4 av = *(const float4*)&As[k][ty * 4];
            float4 bv = *(const float4*)&Bs[k][tx * 4];
            float a[4] = {av.x, av.y, av.z, av.w};
            float b[4] = {bv.x, bv.y, bv.z, bv.w};
#pragma unroll
            for (int i = 0; i < 4; ++i)
#pragma unroll
                for (int j = 0; j < 4; ++j) acc[i][j] = fmaf(a[i], b[j], acc[i][j]);
        }
        __syncthreads();
    }
#pragma unroll
    for (int i = 0; i < 4; ++i) {
        int m = m0 + ty * 4 + i;
        float4 o;
        float* po = (float*)&o;
#pragma unroll
        for (int j = 0; j < 4; ++j) {
            float d = a2[m] + m2[n0 + tx * 4 + j] - 2.0f * acc[i][j];
            po[j] = negBeta * fmaxf(d, 0.0f);
        }
        *(float4*)&S[(size_t)m * Nm + n0 + tx * 4] = o;
    }
}

// ---------- weight GEMM: part[z][b][d] = sum_{n in z-range} w(S[b][n])*mem[n][d]
// TRF 1: w = expf(s-p0)*p1 (softmax);  TRF 2: w = sigmoid(s+p0) (LML)
template <int TRF>
__global__ __launch_bounds__(256) void wgemmG_k(const float* __restrict__ Sx,
                                                const void* __restrict__ memin,
                                                const int* __restrict__ flag,
                                                const float* __restrict__ rowpar,
                                                float* __restrict__ part, int planeSz) {
    __shared__ float Ws[16][68];   // [k][b]
    __shared__ float Bs[16][68];   // [k][d]
    const int tid = threadIdx.x, tx = tid & 15, ty = tid >> 4;
    const int d0 = blockIdx.x * 64, b0 = blockIdx.y * 64;
    const int kz = blockIdx.z * (Nm / KS);
    const int isf = flag[0];

    float acc[4][4];
#pragma unroll
    for (int i = 0; i < 4; ++i)
#pragma unroll
        for (int j = 0; j < 4; ++j) acc[i][j] = 0.f;

    for (int nc = kz; nc < kz + Nm / KS; nc += 16) {
#pragma unroll
        for (int c = tid; c < 1024; c += 256) {
            int r = c >> 4, k = c & 15;       // r: b-row, k: n within chunk
            float s = Sx[(size_t)(b0 + r) * Nm + nc + k];
            float p0 = rowpar[(b0 + r) * 2 + 0];
            float w;
            if constexpr (TRF == 1) w = expf(s - p0) * rowpar[(b0 + r) * 2 + 1];
            else                    w = 1.0f / (1.0f + expf(-(s + p0)));
            Ws[k][r] = w;
            int kk = c >> 6, dd = c & 63;     // mem tile [16][64]
            Bs[kk][dd] = ldin(memin, isf, (size_t)(nc + kk) * Dd + d0 + dd);
        }
        __syncthreads();
#pragma unroll
        for (int k = 0; k < 16; ++k) {
            float4 av = *(const float4*)&Ws[k][ty * 4];
            float4 bv = *(const float4*)&Bs[k][tx * 4];
            float a[4] = {av.x, av.y, av.z, av.w};
            float b[4] = {bv.x, bv.y, bv.z, bv.w};
#pragma unroll
            for (int i = 0; i < 4; ++i)
#pragma unroll
                for (int j = 0; j < 4; ++j) acc[i][j] = fmaf(a[i], b[j], acc[i][j]);
        }
        __syncthreads();
    }
    float* pz = part + (size_t)blockIdx.z * planeSz;
#pragma unroll
    for (int i = 0; i < 4; ++i) {
        float4 o = {acc[i][0], acc[i][1], acc[i][2], acc[i][3]};
        *(float4*)&pz[(size_t)(b0 + ty * 4 + i) * Dd + d0 + tx * 4] = o;
    }
}

// ---------- reduce KS partials -> Rj rows (+ optional row sumsq -> r2w)
__global__ __launch_bounds__(256) void reduceN_k(const float* __restrict__ part,
                                                 float* __restrict__ Rj,
                                                 float* __restrict__ r2w, int doNorm,
                                                 int planeSz) {
    int row = blockIdx.x, tid = threadIdx.x, lane = tid & 63, wave = tid >> 6;
    float sq = 0.f;
    for (int e = tid; e < Dd; e += 256) {
        float s = 0.f;
#pragma unroll
        for (int z = 0; z < KS; ++z) s += part[(size_t)z * planeSz + (size_t)row * Dd + e];
        Rj[(size_t)row * Dd + e] = s;
        sq += s * s;
    }
    if (doNorm) {
        for (int off = 32; off; off >>= 1) sq += __shfl_down(sq, off, 64);
        __shared__ float ws[4];
        if (lane == 0) ws[wave] = sq;
        __syncthreads();
        if (tid == 0) r2w[row] = ws[0] + ws[1] + ws[2] + ws[3];
    }
}

// ---------- per-row stats: top-6 + denom + candidate-set bisection (r7-validated)
__global__ __launch_bounds__(256) void rowstats_k(const float* __restrict__ S,
                                                  float* __restrict__ stats) {
    int b = blockIdx.x, tid = threadIdx.x, lane = tid & 63, wave = tid >> 6;
    __shared__ float cbuf[1024];
    __shared__ int   ccnt;
    __shared__ float tops[256 * 6];
    __shared__ float stop[6];
    __shared__ float wred[16];
    __shared__ float bcast[5];
    const float* srow = S + (size_t)b * Nm;

    float tt[6];
#pragma unroll
    for (int q = 0; q < 6; ++q) tt[q] = -3.4e38f;
    for (int i = tid; i < Nm; i += 256) {
        float v = srow[i];
        if (v > tt[5]) {
            tt[5] = v;
#pragma unroll
            for (int q = 5; q > 0; --q)
                if (tt[q] > tt[q - 1]) { float tm = tt[q]; tt[q] = tt[q - 1]; tt[q - 1] = tm; }
        }
    }
#pragma unroll
    for (int q = 0; q < 6; ++q) tops[tid * 6 + q] = tt[q];
    if (tid == 0) ccnt = 0;
    __syncthreads();
    if (tid == 0) {
        float mt[6];
#pragma unroll
        for (int q = 0; q < 6; ++q) mt[q] = -3.4e38f;
        for (int i = 0; i < 256 * 6; ++i) {
            float v = tops[i];
            if (v > mt[5]) {
                mt[5] = v;
#pragma unroll
                for (int q = 5; q > 0; --q)
                    if (mt[q] > mt[q - 1]) { float tm = mt[q]; mt[q] = mt[q - 1]; mt[q - 1] = tm; }
            }
        }
#pragma unroll
        for (int q = 0; q < 6; ++q) stop[q] = mt[q];
    }
    __syncthreads();

    float smax = stop[0];
    float cutoff = stop[5] - 40.0f;
    float p = 0.f;
    for (int i = tid; i < Nm; i += 256) {
        float v = srow[i];
        p += expf(v - smax);
        if (v >= cutoff) {
            int idx = atomicAdd(&ccnt, 1);
            if (idx < 1024) cbuf[idx] = v;
        }
    }
    for (int off = 32; off; off >>= 1) p += __shfl_down(p, off, 64);
    if (lane == 0) wred[wave] = p;
    __syncthreads();
    if (tid == 0) bcast[4] = wred[0] + wred[1] + wred[2] + wred[3];
    __syncthreads();
    float denom = bcast[4];
    int cnt = min(ccnt, 1024);

    float lo[4], hi[4];
#pragma unroll
    for (int q = 0; q < 4; ++q) { lo[q] = -stop[q + 1] - 7.0f; hi[q] = -stop[q + 2] + 7.0f; }
    for (int it = 0; it < 48; ++it) {
        float mid[4], pp[4] = {0.f, 0.f, 0.f, 0.f};
#pragma unroll
        for (int q = 0; q < 4; ++q) mid[q] = 0.5f * (lo[q] + hi[q]);
        for (int i = tid; i < cnt; i += 256) {
            float v = cbuf[i];
#pragma unroll
            for (int q = 0; q < 4; ++q) pp[q] += 1.0f / (1.0f + expf(-(v + mid[q])));
        }
#pragma unroll
        for (int q = 0; q < 4; ++q) {
            float s = pp[q];
            for (int off = 32; off; off >>= 1) s += __shfl_down(s, off, 64);
            if (lane == 0) wred[wave * 4 + q] = s;
        }
        __syncthreads();
        if (tid == 0)
#pragma unroll
            for (int q = 0; q < 4; ++q) bcast[q] = wred[q] + wred[4 + q] + wred[8 + q] + wred[12 + q];
        __syncthreads();
#pragma unroll
        for (int q = 0; q < 4; ++q) {
            float f = bcast[q] - (float)(q + 2);
            if (f < 0.f) lo[q] = mid[q]; else hi[q] = mid[q];
        }
        __syncthreads();
    }
    if (tid == 0) {
        stats[b * 6 + 0] = smax;
        stats[b * 6 + 1] = denom;
#pragma unroll
        for (int q = 0; q < 4; ++q) stats[b * 6 + 2 + q] = 0.5f * (lo[q] + hi[q]);
    }
}

__global__ __launch_bounds__(256) void rowpar_stage1_k(const float* __restrict__ stats,
                                                       float* __restrict__ rowpar, int jj) {
    int b = blockIdx.x * 256 + threadIdx.x;
    if (b >= Bq) return;
    if (jj == 0) {
        rowpar[b * 2 + 0] = stats[b * 6 + 0];
        rowpar[b * 2 + 1] = 1.0f / stats[b * 6 + 1];
    } else {
        rowpar[b * 2 + 0] = stats[b * 6 + 1 + jj];
        rowpar[b * 2 + 1] = 0.0f;
    }
}

__global__ __launch_bounds__(256) void rowmax_denom_k(const float* __restrict__ S,
                                                      float* __restrict__ rowpar) {
    int b = blockIdx.x, tid = threadIdx.x, lane = tid & 63, wave = tid >> 6;
    __shared__ float wred[4];
    __shared__ float bc[1];
    const float* srow = S + (size_t)b * Nm;
    float mx = -3.4e38f;
    for (int i = tid; i < Nm; i += 256) mx = fmaxf(mx, srow[i]);
    for (int off = 32; off; off >>= 1) mx = fmaxf(mx, __shfl_down(mx, off, 64));
    if (lane == 0) wred[wave] = mx;
    __syncthreads();
    if (tid == 0) bc[0] = fmaxf(fmaxf(wred[0], wred[1]), fmaxf(wred[2], wred[3]));
    __syncthreads();
    mx = bc[0];
    float p = 0.f;
    for (int i = tid; i < Nm; i += 256) p += expf(srow[i] - mx);
    for (int off = 32; off; off >>= 1) p += __shfl_down(p, off, 64);
    __syncthreads();
    if (lane == 0) wred[wave] = p;
    __syncthreads();
    if (tid == 0) {
        rowpar[b * 2 + 0] = mx;
        rowpar[b * 2 + 1] = 1.0f / (wred[0] + wred[1] + wred[2] + wred[3]);
    }
}

// ---------- successive differences (per row) + row norms of resulting planes
__global__ __launch_bounds__(256) void combine_k(float* __restrict__ R,
                                                 float* __restrict__ r2all) {
    int row = blockIdx.x, tid = threadIdx.x, lane = tid & 63, wave = tid >> 6;
    float sq[5] = {0.f, 0.f, 0.f, 0.f, 0.f};
    for (int e = tid; e < Dd; e += 256) {
        size_t idx = (size_t)row * Dd + e;
        float r0 = R[idx], r1 = R[PL + idx], r2v = R[2 * PL + idx],
              r3 = R[3 * PL + idx], r4 = R[4 * PL + idx];
        float o1 = r1 - r0, o2 = r2v - r1, o3 = r3 - r2v, o4 = r4 - r3;
        R[PL + idx] = o1; R[2 * PL + idx] = o2; R[3 * PL + idx] = o3; R[4 * PL + idx] = o4;
        sq[0] += r0 * r0; sq[1] += o1 * o1; sq[2] += o2 * o2; sq[3] += o3 * o3; sq[4] += o4 * o4;
    }
    __shared__ float ws[5][4];
#pragma unroll
    for (int j = 0; j < 5; ++j) {
        float s = sq[j];
        for (int off = 32; off; off >>= 1) s += __shfl_down(s, off, 64);
        if (lane == 0) ws[j][wave] = s;
    }
    __syncthreads();
    if (tid < 5) r2all[tid * Bq + row] = ws[tid][0] + ws[tid][1] + ws[tid][2] + ws[tid][3];
}

__global__ __launch_bounds__(256) void final_k(const float* __restrict__ R,
                                               void* __restrict__ out,
                                               const int* __restrict__ flag) {
    size_t idx = (size_t)blockIdx.x * 256 + threadIdx.x;
    bool isf = flag[0] != 0;
#pragma unroll
    for (int j = 0; j < KK; ++j) {
        float v = R[(size_t)j * PL + idx];
        if (isf) ((float*)out)[idx * KK + j] = v;
        else     ((ushort*)out)[idx * KK + j] = f2b(v);
    }
}

extern "C" void kernel_launch(void* const* d_in, const int* in_sizes, int n_in,
                              void* d_out, int out_size, void* d_ws, size_t ws_size,
                              hipStream_t stream) {
    const void* xin   = d_in[0];
    const void* memin = d_in[1];

    const size_t MiB = 1048576ull, KiB = 1024ull;
    char* ws = (char*)d_ws;
    float* R     = (float*)(ws + 0);                       // 20 MiB [5][Bq][Dd]
    float* m2    = (float*)(ws + 20 * MiB);                // 32 KiB
    float* x2    = (float*)(ws + 20 * MiB + 32 * KiB);     //  8 KiB
    float* stats = (float*)(ws + 20 * MiB + 48 * KiB);     // 48 KiB
    float* rpar  = (float*)(ws + 20 * MiB + 96 * KiB);     // 16 KiB
    int*   flag  = (int*)  (ws + 20 * MiB + 112 * KiB);    //  4 B
    float* r2all = (float*)(ws + 20 * MiB + 128 * KiB);    // 40 KiB [5][Bq]
    float* S     = (float*)(ws + 20 * MiB + 256 * KiB);    // Bc * 32 KiB

    // wgemm split-K partials live in d_out's dead tail (dead before final_k)
    float* part = (float*)d_out;                           // KS * Bc * 512 * 4 <= 16 MiB

    int Bc = 128;
    const int cand[4] = {1024, 512, 256, 128};
    for (int i = 0; i < 4; ++i)
        if (20 * MiB + 256 * KiB + (size_t)cand[i] * Nm * 4 <= ws_size) { Bc = cand[i]; break; }
    const int nChunk = Bq / Bc;
    const int planeSz = Bc * Dd;

    detect_k<<<1, 256, 0, stream>>>((const ushort*)xin, flag);
    norms_k<<<Nm + Bq, 256, 0, stream>>>(xin, memin, flag, x2, m2);

    // ---- stage 1 ----
    for (int c = 0; c < nChunk; ++c) {
        int b0 = c * Bc;
        distF2_k<<<dim3(Nm / 64, Bc / 64), 256, 0, stream>>>(
            xin, flag, 0, memin, S, x2 + b0, m2, b0, -BETA);
        rowstats_k<<<Bc, 256, 0, stream>>>(S, stats + (size_t)b0 * 6);
        for (int jj = 0; jj < KK; ++jj) {
            float* Rj = R + (size_t)jj * PL + (size_t)b0 * Dd;
            rowpar_stage1_k<<<Bq / 256, 256, 0, stream>>>(stats, rpar, jj);
            if (jj == 0)
                wgemmG_k<1><<<dim3(Dd / 64, Bc / 64, KS), 256, 0, stream>>>(
                    S, memin, flag, rpar + (size_t)b0 * 2, part, planeSz);
            else
                wgemmG_k<2><<<dim3(Dd / 64, Bc / 64, KS), 256, 0, stream>>>(
                    S, memin, flag, rpar + (size_t)b0 * 2, part, planeSz);
            reduceN_k<<<Bc, 256, 0, stream>>>(part, Rj, nullptr, 0, planeSz);
        }
    }
    combine_k<<<Bq, 256, 0, stream>>>(R, r2all);

    // ---- hopfield refinement ----
    for (int st = 0; st < STEPS; ++st) {
        for (int jj = 0; jj < KK; ++jj) {
            float* Rj = R + (size_t)jj * PL;
            float* r2j = r2all + (size_t)jj * Bq;
            for (int c = 0; c < nChunk; ++c) {
                int b0 = c * Bc;
                distF2_k<<<dim3(Nm / 64, Bc / 64), 256, 0, stream>>>(
                    Rj, flag, 1, memin, S, r2j + b0, m2, b0, -BETA);
                rowmax_denom_k<<<Bc, 256, 0, stream>>>(S, rpar + (size_t)b0 * 2);
                wgemmG_k<1><<<dim3(Dd / 64, Bc / 64, KS), 256, 0, stream>>>(
                    S, memin, flag, rpar + (size_t)b0 * 2, part, planeSz);
                reduceN_k<<<Bc, 256, 0, stream>>>(
                    part, Rj + (size_t)b0 * Dd, r2j + b0, 1, planeSz);
            }
        }
    }
    final_k<<<(int)(PL / 256), 256, 0, stream>>>(R, d_out, flag);
}